// Round 8
// baseline (674.207 us; speedup 1.0000x reference)
//
#include <hip/hip_runtime.h>

#define NN 50000
#define EE 800000

typedef __bf16 bf16x8 __attribute__((ext_vector_type(8)));
typedef float  f32x4  __attribute__((ext_vector_type(4)));

__device__ __forceinline__ float bf2f(ushort u) {
    union { unsigned int i; float f; } v; v.i = ((unsigned int)u) << 16; return v.f;
}
__device__ __forceinline__ ushort f2bf(float f) {        // RNE
    union { float f; unsigned int i; } v; v.f = f;
    unsigned int u = v.i;
    return (ushort)((u + 0x7FFFu + ((u >> 16) & 1u)) >> 16);
}
__device__ __forceinline__ ushort f2bf_fast(float f) {
    union { float f; unsigned int i; } v; v.f = f;
    return (ushort)((v.i + 0x8000u) >> 16);
}
__device__ __forceinline__ float silu(float x) { return x / (1.0f + __expf(-x)); }

// ---------------------------------------------------------------------------
// Dtype detection (0 = bf16 inputs, 1 = f32 inputs).
// ---------------------------------------------------------------------------
__global__ void detect_kernel(const ushort* __restrict__ xzu, int* __restrict__ flag) {
    __shared__ int cnt;
    if (threadIdx.x == 0) cnt = 0;
    __syncthreads();
    float v = bf2f(xzu[2 * threadIdx.x]);
    bool sane = (v == v) && (fabsf(v) <= 4.0f);
    if (sane) atomicAdd(&cnt, 1);
    __syncthreads();
    if (threadIdx.x == 0) *flag = (cnt >= 192) ? 0 : 1;
}

// ---------------------------------------------------------------------------
// prep: blocks [0,3125) h->bf16 (8 elem/thread); [3125,3712) xz->f32;
//       [3712,6837) degree count
// ---------------------------------------------------------------------------
__global__ void prep_kernel(const void* __restrict__ hsrc, const void* __restrict__ xzsrc,
                            const int* __restrict__ erow, const int* __restrict__ flag,
                            ushort* __restrict__ hb, float* __restrict__ xzf,
                            int* __restrict__ cntI) {
    const bool isf = (*flag != 0);
    int b = blockIdx.x;
    if (b < 3125) {
        int i = (b * 256 + threadIdx.x) * 8;
        uint4 o;
        if (isf) {
            const float* s = (const float*)hsrc + i;
            float4 f0 = *(const float4*)s;
            float4 f1 = *(const float4*)(s + 4);
            o.x = (unsigned int)f2bf(f0.x) | ((unsigned int)f2bf(f0.y) << 16);
            o.y = (unsigned int)f2bf(f0.z) | ((unsigned int)f2bf(f0.w) << 16);
            o.z = (unsigned int)f2bf(f1.x) | ((unsigned int)f2bf(f1.y) << 16);
            o.w = (unsigned int)f2bf(f1.z) | ((unsigned int)f2bf(f1.w) << 16);
        } else {
            o = *(const uint4*)((const ushort*)hsrc + i);
        }
        *(uint4*)(hb + i) = o;
    } else if (b < 3712) {
        int i = (b - 3125) * 256 + threadIdx.x;
        if (i < NN * 3)
            xzf[i] = isf ? ((const float*)xzsrc)[i] : bf2f(((const ushort*)xzsrc)[i]);
    } else {
        int e = (b - 3712) * 256 + threadIdx.x;
        if (e < EE) atomicAdd(&cntI[erow[e]], 1);
    }
}

// ---------------------------------------------------------------------------
// swizzle (blocks 0..47) + misc f32 block (block 48):
// fb: [0:128)=be1 [128:256)=be2 [256:384)=bn1 [384:512)=bn2 [512:640)=We1[256][:]
// ---------------------------------------------------------------------------
__global__ void swizzle_misc_kernel(const void* We1, const void* We2,
                                    const void* Wn1, const void* Wn2,
                                    const void* be1, const void* be2,
                                    const void* bn1, const void* bn2,
                                    const int* __restrict__ flag,
                                    ushort* __restrict__ We1s, ushort* __restrict__ We2s,
                                    ushort* __restrict__ Wn1s, ushort* __restrict__ Wn2s,
                                    float* __restrict__ fb) {
    const bool isf = (*flag != 0);
    if (blockIdx.x == 48) {
        for (int j = threadIdx.x; j < 640; j += 256) {
            int which = j >> 7, k = j & 127;
            const void* src = (which == 0) ? be1 : (which == 1) ? be2 :
                              (which == 2) ? bn1 : (which == 3) ? bn2 : We1;
            size_t idx = (which == 4) ? ((size_t)256 * 128 + k) : (size_t)k;
            fb[j] = isf ? ((const float*)src)[idx] : bf2f(((const ushort*)src)[idx]);
        }
        return;
    }
    int c = blockIdx.x * 256 + threadIdx.x;
    const void* src; ushort* dst; int cl;
    if      (c <  4096) { src = We1; dst = We1s; cl = c;         }
    else if (c <  6144) { src = We2; dst = We2s; cl = c - 4096;  }
    else if (c < 10240) { src = Wn1; dst = Wn1s; cl = c - 6144;  }
    else                { src = Wn2; dst = Wn2s; cl = c - 10240; }
    int l = cl & 63, nt = (cl >> 6) & 7, kc = cl >> 9;
    int kbase = kc * 32 + (l >> 4) * 8;
    int n = nt * 16 + (l & 15);
    ushort tmp[8];
#pragma unroll
    for (int j = 0; j < 8; ++j) {
        size_t idx = (size_t)(kbase + j) * 128 + n;
        tmp[j] = isf ? f2bf(((const float*)src)[idx]) : ((const ushort*)src)[idx];
    }
#pragma unroll
    for (int j = 0; j < 8; ++j) dst[(size_t)cl * 8 + j] = tmp[j];
}

// ---------------------------------------------------------------------------
// Edge kernel: 32-edge tiles, 6 blocks/CU (24 waves), staging via
// global_load_lds (direct-to-LDS gather, XOR swizzle applied to the GLOBAL
// chunk address so the LDS dest stays wave-uniform-base + lane*16).
// ---------------------------------------------------------------------------
typedef __attribute__((address_space(1))) const unsigned int GU;
typedef __attribute__((address_space(3))) unsigned int LU;

__global__ __launch_bounds__(256, 6) void edge_kernel(
    const ushort* __restrict__ hb, const float* __restrict__ xzf,
    const int* __restrict__ erow, const int* __restrict__ ecol,
    const ushort* __restrict__ We1s, const ushort* __restrict__ We2s,
    const float* __restrict__ fb, float* __restrict__ agg) {
    __shared__ __align__(16) ushort sRow[8192];   // 16KB: 64 rows x 256B, slot s of row r = chunk s^(r&7)
    __shared__ __align__(16) ushort sM[4096];     // 8KB: m1[32][128] swizzled
    __shared__ float sDist[2][32];
    __shared__ int   sRowIdx[2][32];

    const int tid = threadIdx.x;
    const int lane = tid & 63, w = tid >> 6;
    const int col = lane & 15, quad = lane >> 4;
    const int nt0 = w * 2;
    const int NT = EE / 32;
    const int stride = gridDim.x;

    const int nA = w * 32 + col, nB = nA + 16;
    const float be1A = fb[nA],       be1B = fb[nB];
    const float be2A = fb[128 + nA], be2B = fb[128 + nB];
    const float wlA  = fb[512 + nA], wlB  = fb[512 + nB];

    bf16x8 B2[8];
#pragma unroll
    for (int kc = 0; kc < 4; ++kc) {
        B2[kc * 2]     = *(const bf16x8*)(We2s + ((kc * 8 + nt0)     * 64 + lane) * 8);
        B2[kc * 2 + 1] = *(const bf16x8*)(We2s + ((kc * 8 + nt0 + 1) * 64 + lane) * 8);
    }

    int par = 0;
    for (int tile = blockIdx.x; tile < NT; tile += stride) {
        const int e0 = tile * 32;
        // ---- staging: direct-to-LDS gather; region (i,w) = rows [(i*4+w)*4, +4) ----
#pragma unroll
        for (int i = 0; i < 4; ++i) {
            int r = (i * 4 + w) * 4 + (lane >> 4);        // 0..63
            int eidx = e0 + (r & 31);
            int node = (r < 32) ? erow[eidx] : ecol[eidx];
            int gch = col ^ (r & 7);                      // swizzled global chunk
            __builtin_amdgcn_global_load_lds(
                (GU*)(hb + (size_t)node * 128 + gch * 8),
                (LU*)(sRow + (size_t)(i * 4 + w) * 512),
                16, 0, 0);
        }
        if (tid < 32) {
            int e = e0 + tid;
            int r = erow[e], c = ecol[e];
            sRowIdx[par][tid] = r;
            float x1 = xzf[3 * r], y1 = xzf[3 * r + 1], z1 = xzf[3 * r + 2];
            float x2 = xzf[3 * c], y2 = xzf[3 * c + 1], z2 = xzf[3 * c + 2];
            float dx = x1 - x2, dy = y1 - y2, dz = z1 - z2;
            float u = (dx * dx + dy * dy + dz * dz) / (2.0f * z1 * z2);
            u = fminf(fmaxf(u, 0.0f), 1.0e6f);
            sDist[par][tid] = __logf(1.0f + u + sqrtf(u * (u + 2.0f)));
        }
        __syncthreads();   // BARRIER-A: lds-loads drained, sRow/meta ready

        // ---- GEMM1: [32,256] @ We1 ----
        f32x4 acc[2][2] = {};
#pragma unroll
        for (int kc = 0; kc < 8; ++kc) {
            bf16x8 b0 = *(const bf16x8*)(We1s + ((kc * 8 + nt0)     * 64 + lane) * 8);
            bf16x8 b1 = *(const bf16x8*)(We1s + ((kc * 8 + nt0 + 1) * 64 + lane) * 8);
#pragma unroll
            for (int g = 0; g < 2; ++g) {
                int r = ((kc < 4) ? 0 : 32) + g * 16 + col;
                int cR = (kc & 3) * 4 + quad;
                bf16x8 a = *(const bf16x8*)(sRow + r * 128 + ((cR ^ (r & 7)) * 8));
                acc[g][0] = __builtin_amdgcn_mfma_f32_16x16x32_bf16(a, b0, acc[g][0], 0, 0, 0);
                acc[g][1] = __builtin_amdgcn_mfma_f32_16x16x32_bf16(a, b1, acc[g][1], 0, 0, 0);
            }
        }
        // ep1
#pragma unroll
        for (int g = 0; g < 2; ++g) {
#pragma unroll
            for (int r4 = 0; r4 < 4; ++r4) {
                int m = g * 16 + quad * 4 + r4;
                float d = sDist[par][m];
                float x0 = acc[g][0][r4] + d * wlA + be1A;
                float x1 = acc[g][1][r4] + d * wlB + be1B;
                sM[m * 128 + ((nA >> 3) ^ (m & 7)) * 8 + (nA & 7)] = f2bf_fast(silu(x0));
                sM[m * 128 + ((nB >> 3) ^ (m & 7)) * 8 + (nB & 7)] = f2bf_fast(silu(x1));
            }
        }
        __syncthreads();   // BARRIER-B

        // ---- GEMM2: m1[32,128] @ We2 (B in regs) ----
        f32x4 acc2[2][2] = {};
#pragma unroll
        for (int kc = 0; kc < 4; ++kc) {
#pragma unroll
            for (int g = 0; g < 2; ++g) {
                int r2 = g * 16 + col;
                int c2 = kc * 4 + quad;
                bf16x8 a = *(const bf16x8*)(sM + r2 * 128 + ((c2 ^ (r2 & 7)) * 8));
                acc2[g][0] = __builtin_amdgcn_mfma_f32_16x16x32_bf16(a, B2[kc * 2],     acc2[g][0], 0, 0, 0);
                acc2[g][1] = __builtin_amdgcn_mfma_f32_16x16x32_bf16(a, B2[kc * 2 + 1], acc2[g][1], 0, 0, 0);
            }
        }
        // ep2: atomics into agg
#pragma unroll
        for (int g = 0; g < 2; ++g) {
#pragma unroll
            for (int r4 = 0; r4 < 4; ++r4) {
                int m = g * 16 + quad * 4 + r4;
                int row = sRowIdx[par][m];
                unsafeAtomicAdd(&agg[(size_t)row * 128 + nA], silu(acc2[g][0][r4] + be2A));
                unsafeAtomicAdd(&agg[(size_t)row * 128 + nB], silu(acc2[g][1][r4] + be2B));
            }
        }
        par ^= 1;
    }
}

// ---------------------------------------------------------------------------
// Node kernel (unchanged from round 7)
// ---------------------------------------------------------------------------
__global__ __launch_bounds__(256, 3) void node_kernel(
    const ushort* __restrict__ hb, const void* __restrict__ hraw,
    const float* __restrict__ agg, const int* __restrict__ cntI,
    const ushort* __restrict__ Wn1s, const ushort* __restrict__ Wn2s,
    const float* __restrict__ fb, const int* __restrict__ flag,
    void* __restrict__ outv) {
    __shared__ __align__(16) ushort sA[16384];
    __shared__ __align__(16) ushort sM[8192];
    const int tid = threadIdx.x;
    const int lane = tid & 63, w = tid >> 6;
    const int col = lane & 15, quad = lane >> 4;
    const int nt0 = w * 2;
    const int ntiles = (NN + 63) / 64;
    const bool isf = (*flag != 0);
    float* outf = (float*)outv;
    ushort* outu = (ushort*)outv;

    const int nA = w * 32 + col, nB = nA + 16;
    const float bn1A = fb[256 + nA], bn1B = fb[256 + nB];
    const float bn2A = fb[384 + nA], bn2B = fb[384 + nB];

    for (int tile = blockIdx.x; tile < ntiles; tile += gridDim.x) {
        __syncthreads();
        const int n0 = tile * 64;
#pragma unroll
        for (int i = 0; i < 8; ++i) {
            int kb = w + 4 * i;
            int node = n0 + lane;
            uint4 v;
            if (node < NN) {
                if (kb < 16) {
                    v = *(const uint4*)(hb + (size_t)node * 128 + kb * 8);
                } else {
                    const float* ap = agg + (size_t)node * 128 + (kb - 16) * 8;
                    float invc = 1.0f / fmaxf((float)cntI[node], 1.0f);
                    float4 f0 = *(const float4*)ap;
                    float4 f1 = *(const float4*)(ap + 4);
                    v.x = (unsigned int)f2bf_fast(f0.x * invc) | ((unsigned int)f2bf_fast(f0.y * invc) << 16);
                    v.y = (unsigned int)f2bf_fast(f0.z * invc) | ((unsigned int)f2bf_fast(f0.w * invc) << 16);
                    v.z = (unsigned int)f2bf_fast(f1.x * invc) | ((unsigned int)f2bf_fast(f1.y * invc) << 16);
                    v.w = (unsigned int)f2bf_fast(f1.z * invc) | ((unsigned int)f2bf_fast(f1.w * invc) << 16);
                }
            } else {
                v = make_uint4(0, 0, 0, 0);
            }
            *(uint4*)(sA + (((quad * 8 + i) * 64) + w * 16 + col) * 8) = v;
        }
        __syncthreads();

        f32x4 acc[4][2] = {};
#pragma unroll
        for (int kc = 0; kc < 8; ++kc) {
            bf16x8 b0 = *(const bf16x8*)(Wn1s + ((kc * 8 + nt0)     * 64 + lane) * 8);
            bf16x8 b1 = *(const bf16x8*)(Wn1s + ((kc * 8 + nt0 + 1) * 64 + lane) * 8);
#pragma unroll
            for (int g = 0; g < 4; ++g) {
                bf16x8 a = *(const bf16x8*)(sA + ((g * 8 + kc) * 64 + lane) * 8);
                acc[g][0] = __builtin_amdgcn_mfma_f32_16x16x32_bf16(a, b0, acc[g][0], 0, 0, 0);
                acc[g][1] = __builtin_amdgcn_mfma_f32_16x16x32_bf16(a, b1, acc[g][1], 0, 0, 0);
            }
        }
#pragma unroll
        for (int g = 0; g < 4; ++g) {
            int base0 = ((g * 4 + w) * 64 + (col >> 3) * 16) * 8 + (col & 7);
#pragma unroll
            for (int r = 0; r < 4; ++r) {
                int mrow = quad * 4 + r;
                sM[base0 + mrow * 8]              = f2bf_fast(silu(acc[g][0][r] + bn1A));
                sM[base0 + 2 * 16 * 8 + mrow * 8] = f2bf_fast(silu(acc[g][1][r] + bn1B));
            }
        }
        __syncthreads();

        f32x4 acc2[4][2] = {};
#pragma unroll
        for (int kc = 0; kc < 4; ++kc) {
            bf16x8 b0 = *(const bf16x8*)(Wn2s + ((kc * 8 + nt0)     * 64 + lane) * 8);
            bf16x8 b1 = *(const bf16x8*)(Wn2s + ((kc * 8 + nt0 + 1) * 64 + lane) * 8);
#pragma unroll
            for (int g = 0; g < 4; ++g) {
                bf16x8 a = *(const bf16x8*)(sM + ((g * 4 + kc) * 64 + lane) * 8);
                acc2[g][0] = __builtin_amdgcn_mfma_f32_16x16x32_bf16(a, b0, acc2[g][0], 0, 0, 0);
                acc2[g][1] = __builtin_amdgcn_mfma_f32_16x16x32_bf16(a, b1, acc2[g][1], 0, 0, 0);
            }
        }
#pragma unroll
        for (int g = 0; g < 4; ++g) {
#pragma unroll
            for (int r = 0; r < 4; ++r) {
                int ml2 = g * 16 + quad * 4 + r;
                int node = n0 + ml2;
                if (node < NN) {
                    size_t oi = (size_t)node * 128;
                    float h0 = isf ? ((const float*)hraw)[oi + nA] : bf2f(((const ushort*)hraw)[oi + nA]);
                    float h1 = isf ? ((const float*)hraw)[oi + nB] : bf2f(((const ushort*)hraw)[oi + nB]);
                    float x0 = acc2[g][0][r] + bn2A + h0;
                    float x1 = acc2[g][1][r] + bn2B + h1;
                    if (isf) { outf[oi + nA] = x0; outf[oi + nB] = x1; }
                    else     { outu[oi + nA] = f2bf_fast(x0); outu[oi + nB] = f2bf_fast(x1); }
                }
            }
        }
    }
}

extern "C" void kernel_launch(void* const* d_in, const int* in_sizes, int n_in,
                              void* d_out, int out_size, void* d_ws, size_t ws_size,
                              hipStream_t stream) {
    const void* xz  = d_in[0];
    const void* h   = d_in[1];
    const void* We1 = d_in[2];
    const void* be1 = d_in[3];
    const void* We2 = d_in[4];
    const void* be2 = d_in[5];
    const void* Wn1 = d_in[6];
    const void* bn1 = d_in[7];
    const void* Wn2 = d_in[8];
    const void* bn2 = d_in[9];
    const int*  ei  = (const int*)d_in[10];
    const int* erow = ei;
    const int* ecol = ei + EE;

    char* base = (char*)d_ws;
    size_t cur = 0;
    auto alloc = [&](size_t bytes) { size_t o = cur; cur = (cur + bytes + 255) & ~(size_t)255; return o; };
    int*    flag = (int*)   (base + alloc(16));
    float*  agg  = (float*) (base + alloc((size_t)NN * 128 * 4));
    int*    cntI = (int*)   (base + alloc((size_t)NN * 4));
    ushort* hb   = (ushort*)(base + alloc((size_t)NN * 128 * 2));
    float*  xzf  = (float*) (base + alloc((size_t)NN * 3 * 4));
    ushort* We1s = (ushort*)(base + alloc(32768 * 2));
    ushort* We2s = (ushort*)(base + alloc(16384 * 2));
    ushort* Wn1s = (ushort*)(base + alloc(32768 * 2));
    ushort* Wn2s = (ushort*)(base + alloc(16384 * 2));
    float*  fb   = (float*) (base + alloc(640 * 4));

    size_t zbytes = (size_t)((char*)cntI - (char*)agg) + (size_t)NN * 4;
    (void)hipMemsetAsync(agg, 0, zbytes, stream);

    detect_kernel<<<1, 256, 0, stream>>>((const ushort*)xz, flag);
    prep_kernel<<<6837, 256, 0, stream>>>(h, xz, erow, flag, hb, xzf, cntI);
    swizzle_misc_kernel<<<49, 256, 0, stream>>>(We1, We2, Wn1, Wn2, be1, be2, bn1, bn2,
                                                flag, We1s, We2s, Wn1s, Wn2s, fb);
    edge_kernel<<<1536, 256, 0, stream>>>(hb, xzf, erow, ecol, We1s, We2s, fb, agg);
    node_kernel<<<782, 256, 0, stream>>>(hb, h, agg, cntI, Wn1s, Wn2s, fb, flag, d_out);
}